// Round 14
// baseline (235.073 us; speedup 1.0000x reference)
//
#include <hip/hip_runtime.h>
#include <hip/hip_bf16.h>

// Pipeline: k_stats (IN mean/rstd) -> k_wprep (conv_w -> bf16 wT2 fragment layout)
//           k_mid (fused IN+dw3x3+pw+bias -> mid bf16 [b][h][c/8][w][c%8])
//           k_conv (implicit-GEMM 3x3 conv, MFMA 16x16x32; wave = 64o x 128pix
//                   acc[4][8]; A and B straight from L2/L1 via coalesced register
//                   loads; A loads NON-TEMPORAL so the streamed weights don't
//                   thrash L1's copy of the reused B tile; no LDS/barriers in loop)

#define EPSV 1e-5f

typedef __attribute__((ext_vector_type(8))) short short8;
typedef __attribute__((ext_vector_type(4))) float f32x4;

__device__ __forceinline__ unsigned short f2bf(float f) {
  union { float f; unsigned int u; } v; v.f = f;
  unsigned int r = v.u + 0x7FFFu + ((v.u >> 16) & 1u);   // RNE
  return (unsigned short)(r >> 16);
}

__device__ __forceinline__ int refl(int i, int n) {
  if (i < 0) i = -i;
  if (i >= n) i = 2 * n - 2 - i;
  return i;
}

// ---------------- kernel 1: instance-norm stats ----------------
__global__ __launch_bounds__(256) void k_stats(const float* __restrict__ x,
                                               float* __restrict__ mean,
                                               float* __restrict__ rstd) {
  int bc = blockIdx.x;
  const float4* xp = (const float4*)(x + (size_t)bc * 4096);
  int tid = threadIdx.x;
  float s = 0.f, q = 0.f;
#pragma unroll
  for (int k = 0; k < 4; ++k) {
    float4 v = xp[tid + k * 256];
    s += v.x + v.y + v.z + v.w;
    q += v.x * v.x + v.y * v.y + v.z * v.z + v.w * v.w;
  }
  __shared__ float s1[256], s2[256];
  s1[tid] = s; s2[tid] = q;
  __syncthreads();
  for (int st = 128; st > 0; st >>= 1) {
    if (tid < st) { s1[tid] += s1[tid + st]; s2[tid] += s2[tid + st]; }
    __syncthreads();
  }
  if (tid == 0) {
    float m = s1[0] * (1.f / 4096.f);
    float var = s2[0] * (1.f / 4096.f) - m * m;
    mean[bc] = m;
    rstd[bc] = rsqrtf(var + EPSV);
  }
}

// ---------------- kernel 2: conv_w[o][c][3][3] -> wT2 MFMA-fragment layout bf16
// flat = (((t*32 + o/16)*16 + c/32)*64 + (g*16 + o%16))*8 + e, g=(c%32)/8, e=c%8
__global__ __launch_bounds__(256) void k_wprep(const float* __restrict__ cw,
                                               unsigned short* __restrict__ wT2) {
  int idx = blockIdx.x * 256 + threadIdx.x;  // 9*512*512
  int e = idx & 7;
  int l15 = (idx >> 3) & 15;
  int g = (idx >> 7) & 3;
  int cq = (idx >> 9) & 15;
  int og = (idx >> 13) & 31;
  int t = idx >> 18;
  int o = og * 16 + l15;
  int c = cq * 32 + g * 8 + e;
  wT2[idx] = f2bf(cw[((size_t)(o * 512 + c)) * 9 + t]);
}

// ---------------- kernel 3: fused IN + dw3x3 + pointwise + bias ----------------
// Output layout: mid[((b*64+h)*64 + c/8)*512 + w*8 + c%8]  (c8-inner, w middle)
__global__ __launch_bounds__(256) void k_mid(const float* __restrict__ x,
                                             const float* __restrict__ wsp,
                                             const float* __restrict__ wpw,
                                             const float* __restrict__ bias,
                                             const float* __restrict__ mean,
                                             const float* __restrict__ rstd,
                                             unsigned short* __restrict__ mid) {
  int bid = blockIdx.x;                      // 8 * 16 * 4 = 512
  int cg = bid & 3;
  int hq = (bid >> 2) & 15;
  int b = bid >> 6;
  int h0 = hq * 4;
  int tid = threadIdx.x;
  int cl = tid & 31, wq = tid >> 5;
  __shared__ union {
    float xs[32 * 391];                      // staged x (c-stride 391, row 65)
    unsigned short tb[4][32][73];            // bf16 transpose buffer (~18.7 KB)
  } smm;

  int rowm[6];
#pragma unroll
  for (int r = 0; r < 6; ++r) rowm[r] = refl(h0 - 1 + r, 64);

  // gather-thread mapping for the coalesced store phase
  int sw = tid & 63, scq = tid >> 6;         // w, c-octet(0..3)

  for (int cc = 0; cc < 4; ++cc) {
    int cbase = cg * 128 + cc * 32;
    __syncthreads();                         // protect tb of prev iter
#pragma unroll
    for (int k = 0; k < 12; ++k) {
      int idx = tid + k * 256;
      int c = idx / 96, rem = idx % 96;
      int r = rem >> 4, w4 = rem & 15;
      float4 v = *(const float4*)(x + ((size_t)(b * 512 + cbase + c)) * 4096 +
                                  rowm[r] * 64 + w4 * 4);
      float* dst = &smm.xs[c * 391 + r * 65 + w4 * 4];
      dst[0] = v.x; dst[1] = v.y; dst[2] = v.z; dst[3] = v.w;
    }
    __syncthreads();

    int gc = b * 512 + cbase + cl;
    float m = mean[gc], rs = rstd[gc];
    float wp = wpw[gc], bv = bias[gc];
    float wk[9], wsum = 0.f;
#pragma unroll
    for (int t = 0; t < 9; ++t) { wk[t] = wsp[(size_t)gc * 9 + t]; wsum += wk[t]; }

    float mv[4][8];                          // results held in regs (xs still live)
    const float* xr = &smm.xs[cl * 391];
#pragma unroll
    for (int r = 0; r < 4; ++r) {
#pragma unroll
      for (int wi = 0; wi < 8; ++wi) {
        int w = wq * 8 + wi;
        int wm = refl(w - 1, 64), wp1 = refl(w + 1, 64);
        float acc = 0.f;
#pragma unroll
        for (int dy = 0; dy < 3; ++dy) {
          const float* row = xr + (r + dy) * 65;
          acc += wk[dy * 3 + 0] * row[wm] + wk[dy * 3 + 1] * row[w] +
                 wk[dy * 3 + 2] * row[wp1];
        }
        mv[r][wi] = (acc - m * wsum) * rs * wp + bv;
      }
    }
    __syncthreads();                         // xs reads done -> overlay tb
#pragma unroll
    for (int r = 0; r < 4; ++r)
#pragma unroll
      for (int wi = 0; wi < 8; ++wi)
        smm.tb[r][cl][wq * 8 + wi] = f2bf(mv[r][wi]);
    __syncthreads();
    // coalesced store: thread (sw, scq) packs 8 channels for one w, 4 rows
#pragma unroll
    for (int r = 0; r < 4; ++r) {
      short8 v;
#pragma unroll
      for (int e = 0; e < 8; ++e)
        v[e] = smm.tb[r][scq * 8 + e][sw];
      *(short8*)(mid + (((size_t)(b * 64 + h0 + r)) * 64 + (cbase >> 3) + scq) * 512
                 + sw * 8) = v;
    }
  }
}

// ---------------- kernel 4: final 3x3 conv, implicit GEMM, all-register ----------------
// grid 256 (1/CU); 8 waves; block = 256 o x (4 rows x 64 w).
// Wave = 64 o x 128 pix (2 rows): acc[4][8]. Per tap: 4 NT A-loads + 8 B-loads,
// all coalesced 16B/lane. A streams (NT, L1-evict-first); B stays L1-resident.
__global__ __launch_bounds__(512, 2) void k_conv(const unsigned short* __restrict__ wT2,
                                                 const unsigned short* __restrict__ mid,
                                                 const float* __restrict__ cb,
                                                 float* __restrict__ out) {
  int nbid = (blockIdx.x & 7) * 32 + (blockIdx.x >> 3);  // XCD-chunked bijection
  int mt = nbid >> 7;                        // 0..1 (256 o each); const per XCD
  int b = (nbid >> 4) & 7;
  int h0 = (nbid & 15) * 4;
  int tid = threadIdx.x;
  int wid = tid >> 6, l = tid & 63;
  int wo = wid & 3, wn = wid >> 2;           // o-quad (64 o), pix-half (2 rows)
  int l15 = l & 15, g = l >> 4;

  __shared__ float epi[64 * 132];            // epilogue transpose only (~34 KB)

  // 4 per-wave mid row base pointers: rows wn*2 + j (reflected), j=0..3 static
  const unsigned short* rowb[4];
#pragma unroll
  for (int j = 0; j < 4; ++j)
    rowb[j] = mid + ((size_t)(b * 64 + refl(h0 - 1 + wn * 2 + j, 64))) * 32768;

  // per-(ww,dx) element offsets within a row: w*8 (c8-inner layout) + g-segment
  int goff[4][3];
#pragma unroll
  for (int ww = 0; ww < 4; ++ww)
#pragma unroll
    for (int dx = 0; dx < 3; ++dx)
      goff[ww][dx] = refl(ww * 16 + l15 + dx - 1, 64) * 8 + g * 512;

  f32x4 acc[4][8];
  f32x4 zero = {0.f, 0.f, 0.f, 0.f};
#pragma unroll
  for (int i = 0; i < 4; ++i)
#pragma unroll
    for (int j = 0; j < 8; ++j) acc[i][j] = zero;

  // per-wave A base: o-groups og = mt*16 + wo*4 + of (wave-private o-slice)
  const unsigned short* wa0 =
      wT2 + ((size_t)((mt * 16 + wo * 4) * 16)) * 512 + l * 8;

  for (int cc = 0; cc < 16; ++cc) {
    const unsigned short* wa = wa0 + (size_t)cc * 512;
    const int cof = cc * 2048;               // cc*4 c-octets * 512

#pragma unroll
    for (int t = 0; t < 9; ++t) {
      const int dy = t / 3, dx = t % 3;      // compile-time (t unrolled)
      // A-fragments: NON-TEMPORAL (streamed once; keep them out of L1)
      short8 a[4];
#pragma unroll
      for (int of = 0; of < 4; ++of)
        a[of] = __builtin_nontemporal_load(
            (const short8*)(wa + (size_t)t * 262144 + of * 8192));
      // B-fragments: normal loads (heavy L1 reuse across taps/dx/waves)
      short8 bf[8];
#pragma unroll
      for (int nf = 0; nf < 8; ++nf)
        bf[nf] = *(const short8*)(rowb[(nf >> 2) + dy] + cof + goff[nf & 3][dx]);

      __builtin_amdgcn_s_setprio(1);
#pragma unroll
      for (int nf = 0; nf < 8; ++nf)
#pragma unroll
        for (int of = 0; of < 4; ++of)
          acc[of][nf] = __builtin_amdgcn_mfma_f32_16x16x32_bf16(
              a[of], bf[nf], acc[of][nf], 0, 0, 0);
      __builtin_amdgcn_s_setprio(0);
    }
  }

  // ---- epilogue: LDS transpose -> coalesced float4 row stores (through L2) ----
#pragma unroll
  for (int p = 0; p < 4; ++p)
#pragma unroll
    for (int s = 0; s < 2; ++s) {
      __syncthreads();
      if (wo == p && wn == s) {              // one wave: 64 o x 128 pix
#pragma unroll
        for (int of = 0; of < 4; ++of)
#pragma unroll
          for (int nf = 0; nf < 8; ++nf) {
            int pix = (nf >> 2) * 64 + (nf & 3) * 16 + l15;  // 0..127
#pragma unroll
            for (int r = 0; r < 4; ++r) {
              int ol = of * 16 + g * 4 + r;  // 0..63
              epi[ol * 132 + pix] = acc[of][nf][r];
            }
          }
      }
      __syncthreads();
#pragma unroll
      for (int it = 0; it < 4; ++it) {
        int idx = tid + it * 512;            // 0..2047 float4 units
        int ol = idx >> 5, rem = idx & 31;
        f32x4 v = *(const f32x4*)&epi[ol * 132 + rem * 4];
        int o = mt * 256 + p * 64 + ol;
        float cbv = cb[o];
        v[0] += cbv; v[1] += cbv; v[2] += cbv; v[3] += cbv;
        int pix = rem * 4;
        int hh = h0 + s * 2 + (pix >> 6);
        int w4 = pix & 63;
        *(f32x4*)(out + (((size_t)(b * 512 + o)) * 64 + hh) * 64 + w4) = v;
      }
    }
}

extern "C" void kernel_launch(void* const* d_in, const int* in_sizes, int n_in,
                              void* d_out, int out_size, void* d_ws, size_t ws_size,
                              hipStream_t stream) {
  const float* x    = (const float*)d_in[0];
  const float* wsp  = (const float*)d_in[1];
  const float* wpw  = (const float*)d_in[2];
  const float* bias = (const float*)d_in[3];
  const float* cw   = (const float*)d_in[4];
  const float* cb   = (const float*)d_in[5];
  float* out = (float*)d_out;

  char* ws = (char*)d_ws;
  float* mean = (float*)ws;                              // 4096 f32
  float* rstd = (float*)(ws + 16384);                    // 4096 f32
  unsigned short* wT2 = (unsigned short*)(ws + 32768);   // 4.5 MB
  unsigned short* mid = (unsigned short*)(ws + 32768 + 9 * 512 * 512 * 2); // 32 MB

  k_stats<<<4096, 256, 0, stream>>>(x, mean, rstd);
  k_wprep<<<9216, 256, 0, stream>>>(cw, wT2);
  k_mid<<<512, 256, 0, stream>>>(x, wsp, wpw, bias, mean, rstd, mid);
  k_conv<<<256, 512, 0, stream>>>(wT2, mid, cb, out);
}

// Round 15
// 229.008 us; speedup vs baseline: 1.0265x; 1.0265x over previous
//
#include <hip/hip_runtime.h>
#include <hip/hip_bf16.h>

// Pipeline: k_stats (IN mean/rstd) -> k_wprep (conv_w -> bf16 wT2 fragment layout)
//           k_mid (fused IN+dw3x3+pw+bias -> mid bf16 [b][h][c/8][w][c%8])
//           k_conv (implicit-GEMM 3x3 conv, MFMA 16x16x32; wave = 64o x 128pix
//                   acc[4][8]; A and B from L1/L2 via coalesced register loads,
//                   DOUBLE-BUFFERED one tap ahead in registers (block-limited
//                   occupancy -> spare reg file is free); no LDS/barriers in loop)

#define EPSV 1e-5f

typedef __attribute__((ext_vector_type(8))) short short8;
typedef __attribute__((ext_vector_type(4))) float f32x4;

__device__ __forceinline__ unsigned short f2bf(float f) {
  union { float f; unsigned int u; } v; v.f = f;
  unsigned int r = v.u + 0x7FFFu + ((v.u >> 16) & 1u);   // RNE
  return (unsigned short)(r >> 16);
}

__device__ __forceinline__ int refl(int i, int n) {
  if (i < 0) i = -i;
  if (i >= n) i = 2 * n - 2 - i;
  return i;
}

// ---------------- kernel 1: instance-norm stats ----------------
__global__ __launch_bounds__(256) void k_stats(const float* __restrict__ x,
                                               float* __restrict__ mean,
                                               float* __restrict__ rstd) {
  int bc = blockIdx.x;
  const float4* xp = (const float4*)(x + (size_t)bc * 4096);
  int tid = threadIdx.x;
  float s = 0.f, q = 0.f;
#pragma unroll
  for (int k = 0; k < 4; ++k) {
    float4 v = xp[tid + k * 256];
    s += v.x + v.y + v.z + v.w;
    q += v.x * v.x + v.y * v.y + v.z * v.z + v.w * v.w;
  }
  __shared__ float s1[256], s2[256];
  s1[tid] = s; s2[tid] = q;
  __syncthreads();
  for (int st = 128; st > 0; st >>= 1) {
    if (tid < st) { s1[tid] += s1[tid + st]; s2[tid] += s2[tid + st]; }
    __syncthreads();
  }
  if (tid == 0) {
    float m = s1[0] * (1.f / 4096.f);
    float var = s2[0] * (1.f / 4096.f) - m * m;
    mean[bc] = m;
    rstd[bc] = rsqrtf(var + EPSV);
  }
}

// ---------------- kernel 2: conv_w[o][c][3][3] -> wT2 MFMA-fragment layout bf16
// flat = (((t*32 + o/16)*16 + c/32)*64 + (g*16 + o%16))*8 + e, g=(c%32)/8, e=c%8
__global__ __launch_bounds__(256) void k_wprep(const float* __restrict__ cw,
                                               unsigned short* __restrict__ wT2) {
  int idx = blockIdx.x * 256 + threadIdx.x;  // 9*512*512
  int e = idx & 7;
  int l15 = (idx >> 3) & 15;
  int g = (idx >> 7) & 3;
  int cq = (idx >> 9) & 15;
  int og = (idx >> 13) & 31;
  int t = idx >> 18;
  int o = og * 16 + l15;
  int c = cq * 32 + g * 8 + e;
  wT2[idx] = f2bf(cw[((size_t)(o * 512 + c)) * 9 + t]);
}

// ---------------- kernel 3: fused IN + dw3x3 + pointwise + bias ----------------
// Output layout: mid[((b*64+h)*64 + c/8)*512 + w*8 + c%8]  (c8-inner, w middle)
__global__ __launch_bounds__(256) void k_mid(const float* __restrict__ x,
                                             const float* __restrict__ wsp,
                                             const float* __restrict__ wpw,
                                             const float* __restrict__ bias,
                                             const float* __restrict__ mean,
                                             const float* __restrict__ rstd,
                                             unsigned short* __restrict__ mid) {
  int bid = blockIdx.x;                      // 8 * 16 * 4 = 512
  int cg = bid & 3;
  int hq = (bid >> 2) & 15;
  int b = bid >> 6;
  int h0 = hq * 4;
  int tid = threadIdx.x;
  int cl = tid & 31, wq = tid >> 5;
  __shared__ union {
    float xs[32 * 391];                      // staged x (c-stride 391, row 65)
    unsigned short tb[4][32][73];            // bf16 transpose buffer (~18.7 KB)
  } smm;

  int rowm[6];
#pragma unroll
  for (int r = 0; r < 6; ++r) rowm[r] = refl(h0 - 1 + r, 64);

  // gather-thread mapping for the coalesced store phase
  int sw = tid & 63, scq = tid >> 6;         // w, c-octet(0..3)

  for (int cc = 0; cc < 4; ++cc) {
    int cbase = cg * 128 + cc * 32;
    __syncthreads();                         // protect tb of prev iter
#pragma unroll
    for (int k = 0; k < 12; ++k) {
      int idx = tid + k * 256;
      int c = idx / 96, rem = idx % 96;
      int r = rem >> 4, w4 = rem & 15;
      float4 v = *(const float4*)(x + ((size_t)(b * 512 + cbase + c)) * 4096 +
                                  rowm[r] * 64 + w4 * 4);
      float* dst = &smm.xs[c * 391 + r * 65 + w4 * 4];
      dst[0] = v.x; dst[1] = v.y; dst[2] = v.z; dst[3] = v.w;
    }
    __syncthreads();

    int gc = b * 512 + cbase + cl;
    float m = mean[gc], rs = rstd[gc];
    float wp = wpw[gc], bv = bias[gc];
    float wk[9], wsum = 0.f;
#pragma unroll
    for (int t = 0; t < 9; ++t) { wk[t] = wsp[(size_t)gc * 9 + t]; wsum += wk[t]; }

    float mv[4][8];                          // results held in regs (xs still live)
    const float* xr = &smm.xs[cl * 391];
#pragma unroll
    for (int r = 0; r < 4; ++r) {
#pragma unroll
      for (int wi = 0; wi < 8; ++wi) {
        int w = wq * 8 + wi;
        int wm = refl(w - 1, 64), wp1 = refl(w + 1, 64);
        float acc = 0.f;
#pragma unroll
        for (int dy = 0; dy < 3; ++dy) {
          const float* row = xr + (r + dy) * 65;
          acc += wk[dy * 3 + 0] * row[wm] + wk[dy * 3 + 1] * row[w] +
                 wk[dy * 3 + 2] * row[wp1];
        }
        mv[r][wi] = (acc - m * wsum) * rs * wp + bv;
      }
    }
    __syncthreads();                         // xs reads done -> overlay tb
#pragma unroll
    for (int r = 0; r < 4; ++r)
#pragma unroll
      for (int wi = 0; wi < 8; ++wi)
        smm.tb[r][cl][wq * 8 + wi] = f2bf(mv[r][wi]);
    __syncthreads();
    // coalesced store: thread (sw, scq) packs 8 channels for one w, 4 rows
#pragma unroll
    for (int r = 0; r < 4; ++r) {
      short8 v;
#pragma unroll
      for (int e = 0; e < 8; ++e)
        v[e] = smm.tb[r][scq * 8 + e][sw];
      *(short8*)(mid + (((size_t)(b * 64 + h0 + r)) * 64 + (cbase >> 3) + scq) * 512
                 + sw * 8) = v;
    }
  }
}

// ---------------- kernel 4: final 3x3 conv, implicit GEMM, all-register ----------------
// grid 256 (1/CU); 8 waves; block = 256 o x (4 rows x 64 w).
// Wave = 64 o x 128 pix (2 rows): acc[4][8]. Operands double-buffered one tap
// ahead in registers: tap t's 32 MFMAs cover tap t+1's 12 operand loads.
__global__ __launch_bounds__(512, 2) void k_conv(const unsigned short* __restrict__ wT2,
                                                 const unsigned short* __restrict__ mid,
                                                 const float* __restrict__ cb,
                                                 float* __restrict__ out) {
  int nbid = (blockIdx.x & 7) * 32 + (blockIdx.x >> 3);  // XCD-chunked bijection
  int mt = nbid >> 7;                        // 0..1 (256 o each); const per XCD
  int b = (nbid >> 4) & 7;
  int h0 = (nbid & 15) * 4;
  int tid = threadIdx.x;
  int wid = tid >> 6, l = tid & 63;
  int wo = wid & 3, wn = wid >> 2;           // o-quad (64 o), pix-half (2 rows)
  int l15 = l & 15, g = l >> 4;

  __shared__ float epi[64 * 132];            // epilogue transpose only (~34 KB)

  // 4 per-wave mid row base pointers: rows wn*2 + j (reflected), j=0..3 static
  const unsigned short* rowb[4];
#pragma unroll
  for (int j = 0; j < 4; ++j)
    rowb[j] = mid + ((size_t)(b * 64 + refl(h0 - 1 + wn * 2 + j, 64))) * 32768;

  // per-(ww,dx) element offsets within a row: w*8 (c8-inner layout) + g-segment
  int goff[4][3];
#pragma unroll
  for (int ww = 0; ww < 4; ++ww)
#pragma unroll
    for (int dx = 0; dx < 3; ++dx)
      goff[ww][dx] = refl(ww * 16 + l15 + dx - 1, 64) * 8 + g * 512;

  f32x4 acc[4][8];
  f32x4 zero = {0.f, 0.f, 0.f, 0.f};
#pragma unroll
  for (int i = 0; i < 4; ++i)
#pragma unroll
    for (int j = 0; j < 8; ++j) acc[i][j] = zero;

  // per-wave A base: o-groups og = mt*16 + wo*4 + of (wave-private o-slice)
  const unsigned short* wa0 =
      wT2 + ((size_t)((mt * 16 + wo * 4) * 16)) * 512 + l * 8;

  // prologue: load tap (cc=0, t=0) operands
  short8 aC[4], bC[8];
#pragma unroll
  for (int of = 0; of < 4; ++of)
    aC[of] = *(const short8*)(wa0 + of * 8192);
#pragma unroll
  for (int nf = 0; nf < 8; ++nf)
    bC[nf] = *(const short8*)(rowb[nf >> 2] + goff[nf & 3][0]);

  for (int cc = 0; cc < 16; ++cc) {
#pragma unroll
    for (int t = 0; t < 9; ++t) {
      // prefetch next tap (tn compile-time; ccn wraps harmlessly at the end)
      const int tn = (t < 8) ? t + 1 : 0;
      const int dyn = tn / 3, dxn = tn % 3;
      const int ccn = (t < 8) ? cc : ((cc + 1) & 15);
      const unsigned short* wan = wa0 + (size_t)tn * 262144 + (size_t)ccn * 512;
      const int cofn = ccn * 2048;
      short8 aN[4], bN[8];
#pragma unroll
      for (int of = 0; of < 4; ++of)
        aN[of] = *(const short8*)(wan + of * 8192);
#pragma unroll
      for (int nf = 0; nf < 8; ++nf)
        bN[nf] = *(const short8*)(rowb[(nf >> 2) + dyn] + cofn + goff[nf & 3][dxn]);

      __builtin_amdgcn_s_setprio(1);
#pragma unroll
      for (int nf = 0; nf < 8; ++nf)
#pragma unroll
        for (int of = 0; of < 4; ++of)
          acc[of][nf] = __builtin_amdgcn_mfma_f32_16x16x32_bf16(
              aC[of], bC[nf], acc[of][nf], 0, 0, 0);
      __builtin_amdgcn_s_setprio(0);

#pragma unroll
      for (int of = 0; of < 4; ++of) aC[of] = aN[of];
#pragma unroll
      for (int nf = 0; nf < 8; ++nf) bC[nf] = bN[nf];
    }
  }

  // ---- epilogue: LDS transpose -> coalesced float4 row stores (through L2) ----
#pragma unroll
  for (int p = 0; p < 4; ++p)
#pragma unroll
    for (int s = 0; s < 2; ++s) {
      __syncthreads();
      if (wo == p && wn == s) {              // one wave: 64 o x 128 pix
#pragma unroll
        for (int of = 0; of < 4; ++of)
#pragma unroll
          for (int nf = 0; nf < 8; ++nf) {
            int pix = (nf >> 2) * 64 + (nf & 3) * 16 + l15;  // 0..127
#pragma unroll
            for (int r = 0; r < 4; ++r) {
              int ol = of * 16 + g * 4 + r;  // 0..63
              epi[ol * 132 + pix] = acc[of][nf][r];
            }
          }
      }
      __syncthreads();
#pragma unroll
      for (int it = 0; it < 4; ++it) {
        int idx = tid + it * 512;            // 0..2047 float4 units
        int ol = idx >> 5, rem = idx & 31;
        f32x4 v = *(const f32x4*)&epi[ol * 132 + rem * 4];
        int o = mt * 256 + p * 64 + ol;
        float cbv = cb[o];
        v[0] += cbv; v[1] += cbv; v[2] += cbv; v[3] += cbv;
        int pix = rem * 4;
        int hh = h0 + s * 2 + (pix >> 6);
        int w4 = pix & 63;
        *(f32x4*)(out + (((size_t)(b * 512 + o)) * 64 + hh) * 64 + w4) = v;
      }
    }
}

extern "C" void kernel_launch(void* const* d_in, const int* in_sizes, int n_in,
                              void* d_out, int out_size, void* d_ws, size_t ws_size,
                              hipStream_t stream) {
  const float* x    = (const float*)d_in[0];
  const float* wsp  = (const float*)d_in[1];
  const float* wpw  = (const float*)d_in[2];
  const float* bias = (const float*)d_in[3];
  const float* cw   = (const float*)d_in[4];
  const float* cb   = (const float*)d_in[5];
  float* out = (float*)d_out;

  char* ws = (char*)d_ws;
  float* mean = (float*)ws;                              // 4096 f32
  float* rstd = (float*)(ws + 16384);                    // 4096 f32
  unsigned short* wT2 = (unsigned short*)(ws + 32768);   // 4.5 MB
  unsigned short* mid = (unsigned short*)(ws + 32768 + 9 * 512 * 512 * 2); // 32 MB

  k_stats<<<4096, 256, 0, stream>>>(x, mean, rstd);
  k_wprep<<<9216, 256, 0, stream>>>(cw, wT2);
  k_mid<<<512, 256, 0, stream>>>(x, wsp, wpw, bias, mean, rstd, mid);
  k_conv<<<256, 512, 0, stream>>>(wT2, mid, cb, out);
}

// Round 16
// 178.572 us; speedup vs baseline: 1.3164x; 1.2824x over previous
//
#include <hip/hip_runtime.h>
#include <hip/hip_bf16.h>

// Pipeline: k_stats (IN mean/rstd) -> k_wprep (conv_w -> bf16 wT2 fragment layout)
//           k_mid (fused IN+dw3x3+pw+bias -> mid bf16 [b][h][w][c])
//           k_conv (implicit-GEMM 3x3 conv, MFMA 16x16x32; wave = 64o x 128pix
//                   acc[4][8]; A from L2 regs, B via gload_lds dbuf; SIMD-mate
//                   waves process taps in ROTATED order (+4 mod 9) so one wave's
//                   load burst hides under the other's MFMA burst)

#define EPSV 1e-5f

typedef __attribute__((ext_vector_type(8))) short short8;
typedef __attribute__((ext_vector_type(4))) float f32x4;

template<int N> struct IC { static constexpr int value = N; };

__device__ __forceinline__ unsigned short f2bf(float f) {
  union { float f; unsigned int u; } v; v.f = f;
  unsigned int r = v.u + 0x7FFFu + ((v.u >> 16) & 1u);   // RNE
  return (unsigned short)(r >> 16);
}

__device__ __forceinline__ int refl(int i, int n) {
  if (i < 0) i = -i;
  if (i >= n) i = 2 * n - 2 - i;
  return i;
}

// ---------------- kernel 1: instance-norm stats ----------------
__global__ __launch_bounds__(256) void k_stats(const float* __restrict__ x,
                                               float* __restrict__ mean,
                                               float* __restrict__ rstd) {
  int bc = blockIdx.x;
  const float4* xp = (const float4*)(x + (size_t)bc * 4096);
  int tid = threadIdx.x;
  float s = 0.f, q = 0.f;
#pragma unroll
  for (int k = 0; k < 4; ++k) {
    float4 v = xp[tid + k * 256];
    s += v.x + v.y + v.z + v.w;
    q += v.x * v.x + v.y * v.y + v.z * v.z + v.w * v.w;
  }
  __shared__ float s1[256], s2[256];
  s1[tid] = s; s2[tid] = q;
  __syncthreads();
  for (int st = 128; st > 0; st >>= 1) {
    if (tid < st) { s1[tid] += s1[tid + st]; s2[tid] += s2[tid + st]; }
    __syncthreads();
  }
  if (tid == 0) {
    float m = s1[0] * (1.f / 4096.f);
    float var = s2[0] * (1.f / 4096.f) - m * m;
    mean[bc] = m;
    rstd[bc] = rsqrtf(var + EPSV);
  }
}

// ---------------- kernel 2: conv_w[o][c][3][3] -> wT2 MFMA-fragment layout bf16
// flat = (((t*32 + o/16)*16 + c/32)*64 + (g*16 + o%16))*8 + e, g=(c%32)/8, e=c%8
__global__ __launch_bounds__(256) void k_wprep(const float* __restrict__ cw,
                                               unsigned short* __restrict__ wT2) {
  int idx = blockIdx.x * 256 + threadIdx.x;  // 9*512*512
  int e = idx & 7;
  int l15 = (idx >> 3) & 15;
  int g = (idx >> 7) & 3;
  int cq = (idx >> 9) & 15;
  int og = (idx >> 13) & 31;
  int t = idx >> 18;
  int o = og * 16 + l15;
  int c = cq * 32 + g * 8 + e;
  wT2[idx] = f2bf(cw[((size_t)(o * 512 + c)) * 9 + t]);
}

// ---------------- kernel 3: fused IN + dw3x3 + pointwise + bias -> mid bf16 [b][h][w][c]
__global__ __launch_bounds__(256) void k_mid(const float* __restrict__ x,
                                             const float* __restrict__ wsp,
                                             const float* __restrict__ wpw,
                                             const float* __restrict__ bias,
                                             const float* __restrict__ mean,
                                             const float* __restrict__ rstd,
                                             unsigned short* __restrict__ mid) {
  int bid = blockIdx.x;                      // 8 * 16 * 4 = 512
  int cg = bid & 3;
  int hq = (bid >> 2) & 15;
  int b = bid >> 6;
  int h0 = hq * 4;
  int tid = threadIdx.x;
  int cl = tid & 31, wq = tid >> 5;
  __shared__ float xs[32 * 391];

  int rowm[6];
#pragma unroll
  for (int r = 0; r < 6; ++r) rowm[r] = refl(h0 - 1 + r, 64);

  for (int cc = 0; cc < 4; ++cc) {
    int cbase = cg * 128 + cc * 32;
    __syncthreads();
#pragma unroll
    for (int k = 0; k < 12; ++k) {
      int idx = tid + k * 256;
      int c = idx / 96, rem = idx % 96;
      int r = rem >> 4, w4 = rem & 15;
      float4 v = *(const float4*)(x + ((size_t)(b * 512 + cbase + c)) * 4096 +
                                  rowm[r] * 64 + w4 * 4);
      float* dst = &xs[c * 391 + r * 65 + w4 * 4];
      dst[0] = v.x; dst[1] = v.y; dst[2] = v.z; dst[3] = v.w;
    }
    __syncthreads();

    int gc = b * 512 + cbase + cl;
    float m = mean[gc], rs = rstd[gc];
    float wp = wpw[gc], bv = bias[gc];
    float wk[9], wsum = 0.f;
#pragma unroll
    for (int t = 0; t < 9; ++t) { wk[t] = wsp[(size_t)gc * 9 + t]; wsum += wk[t]; }

    const float* xr = &xs[cl * 391];
#pragma unroll
    for (int r = 0; r < 4; ++r) {
#pragma unroll
      for (int wi = 0; wi < 8; ++wi) {
        int w = wq * 8 + wi;
        int wm = refl(w - 1, 64), wp1 = refl(w + 1, 64);
        float acc = 0.f;
#pragma unroll
        for (int dy = 0; dy < 3; ++dy) {
          const float* row = xr + (r + dy) * 65;
          acc += wk[dy * 3 + 0] * row[wm] + wk[dy * 3 + 1] * row[w] +
                 wk[dy * 3 + 2] * row[wp1];
        }
        float y = (acc - m * wsum) * rs;
        mid[(((size_t)(b * 64 + h0 + r)) * 64 + w) * 512 + cbase + cl] =
            f2bf(y * wp + bv);
      }
    }
  }
}

// ---------------- kernel 4: final 3x3 conv, implicit GEMM ----------------
// grid 256 (1/CU); 8 waves; block = 256 o x (4 rows x 64 w).
// Wave = 64 o x 128 pix (2 rows): acc[4][8]; per tap 4 A-loads (L2) feed
// 8 ds_read_b128 + 32 MFMA. B staged via gload_lds dbuf (6 halo rows, 24KB).
// SIMD-mates (wn=0 vs wn=1) run taps rotated by 4 -> load/MFMA bursts interleave.
__global__ __launch_bounds__(512, 2) void k_conv(const unsigned short* __restrict__ wT2,
                                                 const unsigned short* __restrict__ mid,
                                                 const float* __restrict__ cb,
                                                 float* __restrict__ out) {
  int nbid = (blockIdx.x & 7) * 32 + (blockIdx.x >> 3);  // XCD-chunked bijection
  int mt = nbid >> 7;                        // 0..1 (256 o each); const per XCD
  int b = (nbid >> 4) & 7;
  int h0 = (nbid & 15) * 4;
  int tid = threadIdx.x;
  int wid = tid >> 6, l = tid & 63;
  int wo = wid & 3, wn = wid >> 2;           // o-quad (64 o), pix-half (2 rows)
  int l15 = l & 15, g = l >> 4;

  __shared__ union {
    unsigned short bbuf[2][6 * 64 * 32];     // 2 x 24 KB (mid tile, 6 halo rows)
    float epi[64 * 132];                     // epilogue transpose (~33 KB)
  } sm;

  int hrow_[6];
#pragma unroll
  for (int r = 0; r < 6; ++r) hrow_[r] = refl(h0 - 1 + r, 64);

  // per-(ww,dx) B byte offsets (reflected w + bank-swizzle slot)
  int boff[4][3];
#pragma unroll
  for (int ww = 0; ww < 4; ++ww)
#pragma unroll
    for (int dx = 0; dx < 3; ++dx) {
      int wr = refl(ww * 16 + l15 + dx - 1, 64);
      int s = g ^ ((wr >> 1) & 3);
      boff[ww][dx] = wr * 64 + s * 16;
    }

  f32x4 acc[4][8];
  f32x4 zero = {0.f, 0.f, 0.f, 0.f};
#pragma unroll
  for (int i = 0; i < 4; ++i)
#pragma unroll
    for (int j = 0; j < 8; ++j) acc[i][j] = zero;

  // B: one 32-c chunk (6 rows x 64 w x 32 c = 24 KB), linear dest, swizzled src
  auto stageB = [&](int pi, int cc) {
    int cb32 = cc * 32;
    char* dstbase = (char*)&sm.bbuf[pi][0];
#pragma unroll
    for (int i = 0; i < 3; ++i) {
      int ld = tid + i * 512;                // 0..1535
      int row = ld >> 8, rem = ld & 255, w = rem >> 2, s = rem & 3;
      int gcg = s ^ ((w >> 1) & 3);
      const unsigned short* src = mid +
          (((size_t)(b * 64 + hrow_[row])) * 64 + w) * 512 + cb32 + gcg * 8;
      __builtin_amdgcn_global_load_lds(
          (const __attribute__((address_space(1))) void*)src,
          (__attribute__((address_space(3))) void*)(dstbase + ld * 16),
          16, 0, 0);
    }
  };

  stageB(0, 0);

  // per-wave A base: o-groups og = mt*16 + wo*4 + of (wave-private o-slice)
  const unsigned short* wa0 =
      wT2 + ((size_t)((mt * 16 + wo * 4) * 16)) * 512 + l * 8;

  for (int cc = 0; cc < 16; ++cc) {
    int pb = cc & 1;
    __syncthreads();                         // B(cc) landed; buf pb^1 free
    if (cc < 15) stageB(pb ^ 1, cc + 1);     // prefetch next chunk (9 taps of cover)
    const char* mb = (const char*)&sm.bbuf[pb][0];
    const unsigned short* wa = wa0 + (size_t)cc * 512;

    auto taps = [&](auto rotc) {
      constexpr int ROT = decltype(rotc)::value;
#pragma unroll
      for (int t = 0; t < 9; ++t) {
        const int tr = (t + ROT) % 9;        // compile-time rotated tap
        const int dy = tr / 3, dx = tr % 3;
        short8 a[4];
#pragma unroll
        for (int of = 0; of < 4; ++of)
          a[of] = *(const short8*)(wa + (size_t)tr * 262144 + of * 8192);

        __builtin_amdgcn_s_setprio(1);
#pragma unroll
        for (int nf = 0; nf < 8; ++nf) {
          const int rowL = wn * 2 + (nf >> 2) + dy;   // 0..5
          short8 bf = *(const short8*)(mb + rowL * 4096 + boff[nf & 3][dx]);
#pragma unroll
          for (int of = 0; of < 4; ++of)
            acc[of][nf] = __builtin_amdgcn_mfma_f32_16x16x32_bf16(
                a[of], bf, acc[of][nf], 0, 0, 0);
        }
        __builtin_amdgcn_s_setprio(0);
      }
    };
    if (wn == 0) taps(IC<0>{});              // SIMD-mates (wid, wid+4) differ in wn
    else         taps(IC<4>{});              // -> de-phased by 4 taps
  }

  // ---- epilogue: LDS transpose -> coalesced float4 row stores (through L2) ----
#pragma unroll
  for (int p = 0; p < 4; ++p)
#pragma unroll
    for (int s = 0; s < 2; ++s) {
      __syncthreads();
      if (wo == p && wn == s) {              // one wave: 64 o x 128 pix
#pragma unroll
        for (int of = 0; of < 4; ++of)
#pragma unroll
          for (int nf = 0; nf < 8; ++nf) {
            int pix = (nf >> 2) * 64 + (nf & 3) * 16 + l15;  // 0..127
#pragma unroll
            for (int r = 0; r < 4; ++r) {
              int ol = of * 16 + g * 4 + r;  // 0..63
              sm.epi[ol * 132 + pix] = acc[of][nf][r];
            }
          }
      }
      __syncthreads();
#pragma unroll
      for (int it = 0; it < 4; ++it) {
        int idx = tid + it * 512;            // 0..2047 float4 units
        int ol = idx >> 5, rem = idx & 31;
        f32x4 v = *(const f32x4*)&sm.epi[ol * 132 + rem * 4];
        int o = mt * 256 + p * 64 + ol;
        float cbv = cb[o];
        v[0] += cbv; v[1] += cbv; v[2] += cbv; v[3] += cbv;
        int pix = rem * 4;
        int hh = h0 + s * 2 + (pix >> 6);
        int w4 = pix & 63;
        *(f32x4*)(out + (((size_t)(b * 512 + o)) * 64 + hh) * 64 + w4) = v;
      }
    }
}

extern "C" void kernel_launch(void* const* d_in, const int* in_sizes, int n_in,
                              void* d_out, int out_size, void* d_ws, size_t ws_size,
                              hipStream_t stream) {
  const float* x    = (const float*)d_in[0];
  const float* wsp  = (const float*)d_in[1];
  const float* wpw  = (const float*)d_in[2];
  const float* bias = (const float*)d_in[3];
  const float* cw   = (const float*)d_in[4];
  const float* cb   = (const float*)d_in[5];
  float* out = (float*)d_out;

  char* ws = (char*)d_ws;
  float* mean = (float*)ws;                              // 4096 f32
  float* rstd = (float*)(ws + 16384);                    // 4096 f32
  unsigned short* wT2 = (unsigned short*)(ws + 32768);   // 4.5 MB
  unsigned short* mid = (unsigned short*)(ws + 32768 + 9 * 512 * 512 * 2); // 32 MB

  k_stats<<<4096, 256, 0, stream>>>(x, mean, rstd);
  k_wprep<<<9216, 256, 0, stream>>>(cw, wT2);
  k_mid<<<512, 256, 0, stream>>>(x, wsp, wpw, bias, mean, rstd, mid);
  k_conv<<<256, 512, 0, stream>>>(wT2, mid, cb, out);
}

// Round 17
// 172.136 us; speedup vs baseline: 1.3656x; 1.0374x over previous
//
#include <hip/hip_runtime.h>
#include <hip/hip_bf16.h>

// Pipeline: k_stats (IN mean/rstd) -> k_wprep (conv_w -> bf16 wT2 fragment layout)
//           k_mid (fused IN+dw3x3+pw+bias -> mid bf16 [b][h][w][c])
//           k_conv (implicit-GEMM 3x3 conv, MFMA 16x16x32; wave = 64o x 128pix
//                   acc[4][8]; A from L2 regs PREFETCHED ONE TAP AHEAD, B via
//                   gload_lds dbuf + per-nf ds_read; SIMD-mate tap rotation)

#define EPSV 1e-5f

typedef __attribute__((ext_vector_type(8))) short short8;
typedef __attribute__((ext_vector_type(4))) float f32x4;

template<int N> struct IC { static constexpr int value = N; };

__device__ __forceinline__ unsigned short f2bf(float f) {
  union { float f; unsigned int u; } v; v.f = f;
  unsigned int r = v.u + 0x7FFFu + ((v.u >> 16) & 1u);   // RNE
  return (unsigned short)(r >> 16);
}

__device__ __forceinline__ int refl(int i, int n) {
  if (i < 0) i = -i;
  if (i >= n) i = 2 * n - 2 - i;
  return i;
}

// ---------------- kernel 1: instance-norm stats ----------------
__global__ __launch_bounds__(256) void k_stats(const float* __restrict__ x,
                                               float* __restrict__ mean,
                                               float* __restrict__ rstd) {
  int bc = blockIdx.x;
  const float4* xp = (const float4*)(x + (size_t)bc * 4096);
  int tid = threadIdx.x;
  float s = 0.f, q = 0.f;
#pragma unroll
  for (int k = 0; k < 4; ++k) {
    float4 v = xp[tid + k * 256];
    s += v.x + v.y + v.z + v.w;
    q += v.x * v.x + v.y * v.y + v.z * v.z + v.w * v.w;
  }
  __shared__ float s1[256], s2[256];
  s1[tid] = s; s2[tid] = q;
  __syncthreads();
  for (int st = 128; st > 0; st >>= 1) {
    if (tid < st) { s1[tid] += s1[tid + st]; s2[tid] += s2[tid + st]; }
    __syncthreads();
  }
  if (tid == 0) {
    float m = s1[0] * (1.f / 4096.f);
    float var = s2[0] * (1.f / 4096.f) - m * m;
    mean[bc] = m;
    rstd[bc] = rsqrtf(var + EPSV);
  }
}

// ---------------- kernel 2: conv_w[o][c][3][3] -> wT2 MFMA-fragment layout bf16
// flat = (((t*32 + o/16)*16 + c/32)*64 + (g*16 + o%16))*8 + e, g=(c%32)/8, e=c%8
__global__ __launch_bounds__(256) void k_wprep(const float* __restrict__ cw,
                                               unsigned short* __restrict__ wT2) {
  int idx = blockIdx.x * 256 + threadIdx.x;  // 9*512*512
  int e = idx & 7;
  int l15 = (idx >> 3) & 15;
  int g = (idx >> 7) & 3;
  int cq = (idx >> 9) & 15;
  int og = (idx >> 13) & 31;
  int t = idx >> 18;
  int o = og * 16 + l15;
  int c = cq * 32 + g * 8 + e;
  wT2[idx] = f2bf(cw[((size_t)(o * 512 + c)) * 9 + t]);
}

// ---------------- kernel 3: fused IN + dw3x3 + pointwise + bias -> mid bf16 [b][h][w][c]
__global__ __launch_bounds__(256) void k_mid(const float* __restrict__ x,
                                             const float* __restrict__ wsp,
                                             const float* __restrict__ wpw,
                                             const float* __restrict__ bias,
                                             const float* __restrict__ mean,
                                             const float* __restrict__ rstd,
                                             unsigned short* __restrict__ mid) {
  int bid = blockIdx.x;                      // 8 * 16 * 4 = 512
  int cg = bid & 3;
  int hq = (bid >> 2) & 15;
  int b = bid >> 6;
  int h0 = hq * 4;
  int tid = threadIdx.x;
  int cl = tid & 31, wq = tid >> 5;
  __shared__ float xs[32 * 391];

  int rowm[6];
#pragma unroll
  for (int r = 0; r < 6; ++r) rowm[r] = refl(h0 - 1 + r, 64);

  for (int cc = 0; cc < 4; ++cc) {
    int cbase = cg * 128 + cc * 32;
    __syncthreads();
#pragma unroll
    for (int k = 0; k < 12; ++k) {
      int idx = tid + k * 256;
      int c = idx / 96, rem = idx % 96;
      int r = rem >> 4, w4 = rem & 15;
      float4 v = *(const float4*)(x + ((size_t)(b * 512 + cbase + c)) * 4096 +
                                  rowm[r] * 64 + w4 * 4);
      float* dst = &xs[c * 391 + r * 65 + w4 * 4];
      dst[0] = v.x; dst[1] = v.y; dst[2] = v.z; dst[3] = v.w;
    }
    __syncthreads();

    int gc = b * 512 + cbase + cl;
    float m = mean[gc], rs = rstd[gc];
    float wp = wpw[gc], bv = bias[gc];
    float wk[9], wsum = 0.f;
#pragma unroll
    for (int t = 0; t < 9; ++t) { wk[t] = wsp[(size_t)gc * 9 + t]; wsum += wk[t]; }

    const float* xr = &xs[cl * 391];
#pragma unroll
    for (int r = 0; r < 4; ++r) {
#pragma unroll
      for (int wi = 0; wi < 8; ++wi) {
        int w = wq * 8 + wi;
        int wm = refl(w - 1, 64), wp1 = refl(w + 1, 64);
        float acc = 0.f;
#pragma unroll
        for (int dy = 0; dy < 3; ++dy) {
          const float* row = xr + (r + dy) * 65;
          acc += wk[dy * 3 + 0] * row[wm] + wk[dy * 3 + 1] * row[w] +
                 wk[dy * 3 + 2] * row[wp1];
        }
        float y = (acc - m * wsum) * rs;
        mid[(((size_t)(b * 64 + h0 + r)) * 64 + w) * 512 + cbase + cl] =
            f2bf(y * wp + bv);
      }
    }
  }
}

// ---------------- kernel 4: final 3x3 conv, implicit GEMM ----------------
// grid 256 (1/CU); 8 waves; block = 256 o x (4 rows x 64 w).
// Wave = 64 o x 128 pix (2 rows): acc[4][8]; A prefetched one tap ahead (aN),
// B via gload_lds dbuf + per-nf ds_read (compiler-pipelined lgkmcnt).
__global__ __launch_bounds__(512, 2) void k_conv(const unsigned short* __restrict__ wT2,
                                                 const unsigned short* __restrict__ mid,
                                                 const float* __restrict__ cb,
                                                 float* __restrict__ out) {
  int nbid = (blockIdx.x & 7) * 32 + (blockIdx.x >> 3);  // XCD-chunked bijection
  int mt = nbid >> 7;                        // 0..1 (256 o each); const per XCD
  int b = (nbid >> 4) & 7;
  int h0 = (nbid & 15) * 4;
  int tid = threadIdx.x;
  int wid = tid >> 6, l = tid & 63;
  int wo = wid & 3, wn = wid >> 2;           // o-quad (64 o), pix-half (2 rows)
  int l15 = l & 15, g = l >> 4;

  __shared__ union {
    unsigned short bbuf[2][6 * 64 * 32];     // 2 x 24 KB (mid tile, 6 halo rows)
    float epi[64 * 132];                     // epilogue transpose (~33 KB)
  } sm;

  int hrow_[6];
#pragma unroll
  for (int r = 0; r < 6; ++r) hrow_[r] = refl(h0 - 1 + r, 64);

  // per-(ww,dx) B byte offsets (reflected w + bank-swizzle slot)
  int boff[4][3];
#pragma unroll
  for (int ww = 0; ww < 4; ++ww)
#pragma unroll
    for (int dx = 0; dx < 3; ++dx) {
      int wr = refl(ww * 16 + l15 + dx - 1, 64);
      int s = g ^ ((wr >> 1) & 3);
      boff[ww][dx] = wr * 64 + s * 16;
    }

  f32x4 acc[4][8];
  f32x4 zero = {0.f, 0.f, 0.f, 0.f};
#pragma unroll
  for (int i = 0; i < 4; ++i)
#pragma unroll
    for (int j = 0; j < 8; ++j) acc[i][j] = zero;

  // B: one 32-c chunk (6 rows x 64 w x 32 c = 24 KB), linear dest, swizzled src
  auto stageB = [&](int pi, int cc) {
    int cb32 = cc * 32;
    char* dstbase = (char*)&sm.bbuf[pi][0];
#pragma unroll
    for (int i = 0; i < 3; ++i) {
      int ld = tid + i * 512;                // 0..1535
      int row = ld >> 8, rem = ld & 255, w = rem >> 2, s = rem & 3;
      int gcg = s ^ ((w >> 1) & 3);
      const unsigned short* src = mid +
          (((size_t)(b * 64 + hrow_[row])) * 64 + w) * 512 + cb32 + gcg * 8;
      __builtin_amdgcn_global_load_lds(
          (const __attribute__((address_space(1))) void*)src,
          (__attribute__((address_space(3))) void*)(dstbase + ld * 16),
          16, 0, 0);
    }
  };

  stageB(0, 0);

  // per-wave A base: o-groups og = mt*16 + wo*4 + of (wave-private o-slice)
  const unsigned short* wa0 =
      wT2 + ((size_t)((mt * 16 + wo * 4) * 16)) * 512 + l * 8;

  // prologue: load A for the first executed tap (rot = wn*4), chunk 0
  short8 aC[4];
  {
    const unsigned short* wp0 = wa0 + (size_t)(wn * 4) * 262144;
#pragma unroll
    for (int of = 0; of < 4; ++of)
      aC[of] = *(const short8*)(wp0 + of * 8192);
  }

  for (int cc = 0; cc < 16; ++cc) {
    int pb = cc & 1;
    __syncthreads();                         // B(cc) landed; buf pb^1 free
    if (cc < 15) stageB(pb ^ 1, cc + 1);     // prefetch next chunk (9 taps of cover)
    const char* mb = (const char*)&sm.bbuf[pb][0];

    auto taps = [&](auto rotc) {
      constexpr int ROT = decltype(rotc)::value;
#pragma unroll
      for (int t = 0; t < 9; ++t) {
        const int tr = (t + ROT) % 9;        // compile-time rotated tap
        const int dy = tr / 3, dx = tr % 3;

        // prefetch NEXT tap's A (next chunk's first tap when t==8; wraps safely)
        const int trn = (t + 1 + ROT) % 9;
        const int ccn = (t < 8) ? cc : ((cc + 1) & 15);
        const unsigned short* wan =
            wa0 + (size_t)trn * 262144 + (size_t)ccn * 512;
        short8 aN[4];
#pragma unroll
        for (int of = 0; of < 4; ++of)
          aN[of] = *(const short8*)(wan + of * 8192);

        __builtin_amdgcn_s_setprio(1);
#pragma unroll
        for (int nf = 0; nf < 8; ++nf) {
          const int rowL = wn * 2 + (nf >> 2) + dy;   // 0..5
          short8 bf = *(const short8*)(mb + rowL * 4096 + boff[nf & 3][dx]);
#pragma unroll
          for (int of = 0; of < 4; ++of)
            acc[of][nf] = __builtin_amdgcn_mfma_f32_16x16x32_bf16(
                aC[of], bf, acc[of][nf], 0, 0, 0);
        }
        __builtin_amdgcn_s_setprio(0);
#pragma unroll
        for (int of = 0; of < 4; ++of) aC[of] = aN[of];
      }
    };
    if (wn == 0) taps(IC<0>{});              // SIMD-mates (wid, wid+4) differ in wn
    else         taps(IC<4>{});              // -> de-phased by 4 taps
  }

  // ---- epilogue: LDS transpose -> coalesced float4 row stores (through L2) ----
#pragma unroll
  for (int p = 0; p < 4; ++p)
#pragma unroll
    for (int s = 0; s < 2; ++s) {
      __syncthreads();
      if (wo == p && wn == s) {              // one wave: 64 o x 128 pix
#pragma unroll
        for (int of = 0; of < 4; ++of)
#pragma unroll
          for (int nf = 0; nf < 8; ++nf) {
            int pix = (nf >> 2) * 64 + (nf & 3) * 16 + l15;  // 0..127
#pragma unroll
            for (int r = 0; r < 4; ++r) {
              int ol = of * 16 + g * 4 + r;  // 0..63
              sm.epi[ol * 132 + pix] = acc[of][nf][r];
            }
          }
      }
      __syncthreads();
#pragma unroll
      for (int it = 0; it < 4; ++it) {
        int idx = tid + it * 512;            // 0..2047 float4 units
        int ol = idx >> 5, rem = idx & 31;
        f32x4 v = *(const f32x4*)&sm.epi[ol * 132 + rem * 4];
        int o = mt * 256 + p * 64 + ol;
        float cbv = cb[o];
        v[0] += cbv; v[1] += cbv; v[2] += cbv; v[3] += cbv;
        int pix = rem * 4;
        int hh = h0 + s * 2 + (pix >> 6);
        int w4 = pix & 63;
        *(f32x4*)(out + (((size_t)(b * 512 + o)) * 64 + hh) * 64 + w4) = v;
      }
    }
}

extern "C" void kernel_launch(void* const* d_in, const int* in_sizes, int n_in,
                              void* d_out, int out_size, void* d_ws, size_t ws_size,
                              hipStream_t stream) {
  const float* x    = (const float*)d_in[0];
  const float* wsp  = (const float*)d_in[1];
  const float* wpw  = (const float*)d_in[2];
  const float* bias = (const float*)d_in[3];
  const float* cw   = (const float*)d_in[4];
  const float* cb   = (const float*)d_in[5];
  float* out = (float*)d_out;

  char* ws = (char*)d_ws;
  float* mean = (float*)ws;                              // 4096 f32
  float* rstd = (float*)(ws + 16384);                    // 4096 f32
  unsigned short* wT2 = (unsigned short*)(ws + 32768);   // 4.5 MB
  unsigned short* mid = (unsigned short*)(ws + 32768 + 9 * 512 * 512 * 2); // 32 MB

  k_stats<<<4096, 256, 0, stream>>>(x, mean, rstd);
  k_wprep<<<9216, 256, 0, stream>>>(cw, wT2);
  k_mid<<<512, 256, 0, stream>>>(x, wsp, wpw, bias, mean, rstd, mid);
  k_conv<<<256, 512, 0, stream>>>(wT2, mid, cb, out);
}

// Round 18
// 171.443 us; speedup vs baseline: 1.3711x; 1.0040x over previous
//
#include <hip/hip_runtime.h>
#include <hip/hip_bf16.h>

// Pipeline: k_stats (IN mean/rstd) -> k_wprep (conv_w -> bf16 wT2 fragment layout)
//           k_mid (fused IN+dw3x3+pw+bias -> mid bf16 [b][h][w][c])
//           k_conv (implicit-GEMM 3x3 conv, MFMA 16x16x32; wave = 64o x 128pix
//                   acc[4][8]; A prefetched one tap ahead (VMEM), B ds_reads
//                   software-pipelined one fragment ahead (LDS latency hides
//                   under the previous fragment's MFMA cluster))

#define EPSV 1e-5f

typedef __attribute__((ext_vector_type(8))) short short8;
typedef __attribute__((ext_vector_type(4))) float f32x4;

template<int N> struct IC { static constexpr int value = N; };

__device__ __forceinline__ unsigned short f2bf(float f) {
  union { float f; unsigned int u; } v; v.f = f;
  unsigned int r = v.u + 0x7FFFu + ((v.u >> 16) & 1u);   // RNE
  return (unsigned short)(r >> 16);
}

__device__ __forceinline__ int refl(int i, int n) {
  if (i < 0) i = -i;
  if (i >= n) i = 2 * n - 2 - i;
  return i;
}

// ---------------- kernel 1: instance-norm stats ----------------
__global__ __launch_bounds__(256) void k_stats(const float* __restrict__ x,
                                               float* __restrict__ mean,
                                               float* __restrict__ rstd) {
  int bc = blockIdx.x;
  const float4* xp = (const float4*)(x + (size_t)bc * 4096);
  int tid = threadIdx.x;
  float s = 0.f, q = 0.f;
#pragma unroll
  for (int k = 0; k < 4; ++k) {
    float4 v = xp[tid + k * 256];
    s += v.x + v.y + v.z + v.w;
    q += v.x * v.x + v.y * v.y + v.z * v.z + v.w * v.w;
  }
  __shared__ float s1[256], s2[256];
  s1[tid] = s; s2[tid] = q;
  __syncthreads();
  for (int st = 128; st > 0; st >>= 1) {
    if (tid < st) { s1[tid] += s1[tid + st]; s2[tid] += s2[tid + st]; }
    __syncthreads();
  }
  if (tid == 0) {
    float m = s1[0] * (1.f / 4096.f);
    float var = s2[0] * (1.f / 4096.f) - m * m;
    mean[bc] = m;
    rstd[bc] = rsqrtf(var + EPSV);
  }
}

// ---------------- kernel 2: conv_w[o][c][3][3] -> wT2 MFMA-fragment layout bf16
// flat = (((t*32 + o/16)*16 + c/32)*64 + (g*16 + o%16))*8 + e, g=(c%32)/8, e=c%8
__global__ __launch_bounds__(256) void k_wprep(const float* __restrict__ cw,
                                               unsigned short* __restrict__ wT2) {
  int idx = blockIdx.x * 256 + threadIdx.x;  // 9*512*512
  int e = idx & 7;
  int l15 = (idx >> 3) & 15;
  int g = (idx >> 7) & 3;
  int cq = (idx >> 9) & 15;
  int og = (idx >> 13) & 31;
  int t = idx >> 18;
  int o = og * 16 + l15;
  int c = cq * 32 + g * 8 + e;
  wT2[idx] = f2bf(cw[((size_t)(o * 512 + c)) * 9 + t]);
}

// ---------------- kernel 3: fused IN + dw3x3 + pointwise + bias -> mid bf16 [b][h][w][c]
__global__ __launch_bounds__(256) void k_mid(const float* __restrict__ x,
                                             const float* __restrict__ wsp,
                                             const float* __restrict__ wpw,
                                             const float* __restrict__ bias,
                                             const float* __restrict__ mean,
                                             const float* __restrict__ rstd,
                                             unsigned short* __restrict__ mid) {
  int bid = blockIdx.x;                      // 8 * 16 * 4 = 512
  int cg = bid & 3;
  int hq = (bid >> 2) & 15;
  int b = bid >> 6;
  int h0 = hq * 4;
  int tid = threadIdx.x;
  int cl = tid & 31, wq = tid >> 5;
  __shared__ float xs[32 * 391];

  int rowm[6];
#pragma unroll
  for (int r = 0; r < 6; ++r) rowm[r] = refl(h0 - 1 + r, 64);

  for (int cc = 0; cc < 4; ++cc) {
    int cbase = cg * 128 + cc * 32;
    __syncthreads();
#pragma unroll
    for (int k = 0; k < 12; ++k) {
      int idx = tid + k * 256;
      int c = idx / 96, rem = idx % 96;
      int r = rem >> 4, w4 = rem & 15;
      float4 v = *(const float4*)(x + ((size_t)(b * 512 + cbase + c)) * 4096 +
                                  rowm[r] * 64 + w4 * 4);
      float* dst = &xs[c * 391 + r * 65 + w4 * 4];
      dst[0] = v.x; dst[1] = v.y; dst[2] = v.z; dst[3] = v.w;
    }
    __syncthreads();

    int gc = b * 512 + cbase + cl;
    float m = mean[gc], rs = rstd[gc];
    float wp = wpw[gc], bv = bias[gc];
    float wk[9], wsum = 0.f;
#pragma unroll
    for (int t = 0; t < 9; ++t) { wk[t] = wsp[(size_t)gc * 9 + t]; wsum += wk[t]; }

    const float* xr = &xs[cl * 391];
#pragma unroll
    for (int r = 0; r < 4; ++r) {
#pragma unroll
      for (int wi = 0; wi < 8; ++wi) {
        int w = wq * 8 + wi;
        int wm = refl(w - 1, 64), wp1 = refl(w + 1, 64);
        float acc = 0.f;
#pragma unroll
        for (int dy = 0; dy < 3; ++dy) {
          const float* row = xr + (r + dy) * 65;
          acc += wk[dy * 3 + 0] * row[wm] + wk[dy * 3 + 1] * row[w] +
                 wk[dy * 3 + 2] * row[wp1];
        }
        float y = (acc - m * wsum) * rs;
        mid[(((size_t)(b * 64 + h0 + r)) * 64 + w) * 512 + cbase + cl] =
            f2bf(y * wp + bv);
      }
    }
  }
}

// ---------------- kernel 4: final 3x3 conv, implicit GEMM ----------------
// grid 256 (1/CU); 8 waves; block = 256 o x (4 rows x 64 w).
// Wave = 64 o x 128 pix (2 rows): acc[4][8]; A prefetched one tap ahead,
// B ds_reads pipelined one fragment ahead (bfC/bfN). Rotation kept.
__global__ __launch_bounds__(512, 2) void k_conv(const unsigned short* __restrict__ wT2,
                                                 const unsigned short* __restrict__ mid,
                                                 const float* __restrict__ cb,
                                                 float* __restrict__ out) {
  int nbid = (blockIdx.x & 7) * 32 + (blockIdx.x >> 3);  // XCD-chunked bijection
  int mt = nbid >> 7;                        // 0..1 (256 o each); const per XCD
  int b = (nbid >> 4) & 7;
  int h0 = (nbid & 15) * 4;
  int tid = threadIdx.x;
  int wid = tid >> 6, l = tid & 63;
  int wo = wid & 3, wn = wid >> 2;           // o-quad (64 o), pix-half (2 rows)
  int l15 = l & 15, g = l >> 4;

  __shared__ union {
    unsigned short bbuf[2][6 * 64 * 32];     // 2 x 24 KB (mid tile, 6 halo rows)
    float epi[64 * 132];                     // epilogue transpose (~33 KB)
  } sm;

  int hrow_[6];
#pragma unroll
  for (int r = 0; r < 6; ++r) hrow_[r] = refl(h0 - 1 + r, 64);

  // per-(ww,dx) B byte offsets (reflected w + bank-swizzle slot)
  int boff[4][3];
#pragma unroll
  for (int ww = 0; ww < 4; ++ww)
#pragma unroll
    for (int dx = 0; dx < 3; ++dx) {
      int wr = refl(ww * 16 + l15 + dx - 1, 64);
      int s = g ^ ((wr >> 1) & 3);
      boff[ww][dx] = wr * 64 + s * 16;
    }

  f32x4 acc[4][8];
  f32x4 zero = {0.f, 0.f, 0.f, 0.f};
#pragma unroll
  for (int i = 0; i < 4; ++i)
#pragma unroll
    for (int j = 0; j < 8; ++j) acc[i][j] = zero;

  // B: one 32-c chunk (6 rows x 64 w x 32 c = 24 KB), linear dest, swizzled src
  auto stageB = [&](int pi, int cc) {
    int cb32 = cc * 32;
    char* dstbase = (char*)&sm.bbuf[pi][0];
#pragma unroll
    for (int i = 0; i < 3; ++i) {
      int ld = tid + i * 512;                // 0..1535
      int row = ld >> 8, rem = ld & 255, w = rem >> 2, s = rem & 3;
      int gcg = s ^ ((w >> 1) & 3);
      const unsigned short* src = mid +
          (((size_t)(b * 64 + hrow_[row])) * 64 + w) * 512 + cb32 + gcg * 8;
      __builtin_amdgcn_global_load_lds(
          (const __attribute__((address_space(1))) void*)src,
          (__attribute__((address_space(3))) void*)(dstbase + ld * 16),
          16, 0, 0);
    }
  };

  stageB(0, 0);

  // per-wave A base: o-groups og = mt*16 + wo*4 + of (wave-private o-slice)
  const unsigned short* wa0 =
      wT2 + ((size_t)((mt * 16 + wo * 4) * 16)) * 512 + l * 8;

  // prologue: load A for the first executed tap (rot = wn*4), chunk 0
  short8 aC[4];
  {
    const unsigned short* wp0 = wa0 + (size_t)(wn * 4) * 262144;
#pragma unroll
    for (int of = 0; of < 4; ++of)
      aC[of] = *(const short8*)(wp0 + of * 8192);
  }

  for (int cc = 0; cc < 16; ++cc) {
    int pb = cc & 1;
    __syncthreads();                         // B(cc) landed; buf pb^1 free
    if (cc < 15) stageB(pb ^ 1, cc + 1);     // prefetch next chunk (9 taps of cover)
    const char* mb = (const char*)&sm.bbuf[pb][0];

    auto taps = [&](auto rotc) {
      constexpr int ROT = decltype(rotc)::value;
      // prime B pipeline: first tap's nf=0 fragment
      {
        const int tr0 = ROT % 9;
        const int dy0 = tr0 / 3, dx0 = tr0 % 3;
      }
      const int dy0 = (ROT % 9) / 3, dx0 = (ROT % 9) % 3;
      short8 bfC = *(const short8*)(mb + (wn * 2 + dy0) * 4096 + boff[0][dx0]);
#pragma unroll
      for (int t = 0; t < 9; ++t) {
        const int tr = (t + ROT) % 9;        // compile-time rotated tap
        const int dy = tr / 3, dx = tr % 3;

        // prefetch NEXT tap's A (next chunk's first tap when t==8; wraps safely)
        const int trn = (t + 1 + ROT) % 9;
        const int dyn = trn / 3, dxn = trn % 3;
        const int ccn = (t < 8) ? cc : ((cc + 1) & 15);
        const unsigned short* wan =
            wa0 + (size_t)trn * 262144 + (size_t)ccn * 512;
        short8 aN[4];
#pragma unroll
        for (int of = 0; of < 4; ++of)
          aN[of] = *(const short8*)(wan + of * 8192);

        __builtin_amdgcn_s_setprio(1);
#pragma unroll
        for (int nf = 0; nf < 8; ++nf) {
          // prefetch NEXT fragment's B while this fragment's MFMAs run
          short8 bfN;
          if (nf < 7) {
            const int rowLn = wn * 2 + ((nf + 1) >> 2) + dy;
            bfN = *(const short8*)(mb + rowLn * 4096 + boff[(nf + 1) & 3][dx]);
          } else if (t < 8) {
            const int rowLn = wn * 2 + dyn;  // next tap's nf=0
            bfN = *(const short8*)(mb + rowLn * 4096 + boff[0][dxn]);
          } else {
            bfN = bfC;                       // chunk end: no cross-chunk prefetch
          }
#pragma unroll
          for (int of = 0; of < 4; ++of)
            acc[of][nf] = __builtin_amdgcn_mfma_f32_16x16x32_bf16(
                aC[of], bfC, acc[of][nf], 0, 0, 0);
          bfC = bfN;
        }
        __builtin_amdgcn_s_setprio(0);
#pragma unroll
        for (int of = 0; of < 4; ++of) aC[of] = aN[of];
      }
    };
    if (wn == 0) taps(IC<0>{});              // SIMD-mates (wid, wid+4) differ in wn
    else         taps(IC<4>{});              // -> de-phased by 4 taps
  }

  // ---- epilogue: LDS transpose -> coalesced float4 row stores (through L2) ----
#pragma unroll
  for (int p = 0; p < 4; ++p)
#pragma unroll
    for (int s = 0; s < 2; ++s) {
      __syncthreads();
      if (wo == p && wn == s) {              // one wave: 64 o x 128 pix
#pragma unroll
        for (int of = 0; of < 4; ++of)
#pragma unroll
          for (int nf = 0; nf < 8; ++nf) {
            int pix = (nf >> 2) * 64 + (nf & 3) * 16 + l15;  // 0..127
#pragma unroll
            for (int r = 0; r < 4; ++r) {
              int ol = of * 16 + g * 4 + r;  // 0..63
              sm.epi[ol * 132 + pix] = acc[of][nf][r];
            }
          }
      }
      __syncthreads();
#pragma unroll
      for (int it = 0; it < 4; ++it) {
        int idx = tid + it * 512;            // 0..2047 float4 units
        int ol = idx >> 5, rem = idx & 31;
        f32x4 v = *(const f32x4*)&sm.epi[ol * 132 + rem * 4];
        int o = mt * 256 + p * 64 + ol;
        float cbv = cb[o];
        v[0] += cbv; v[1] += cbv; v[2] += cbv; v[3] += cbv;
        int pix = rem * 4;
        int hh = h0 + s * 2 + (pix >> 6);
        int w4 = pix & 63;
        *(f32x4*)(out + (((size_t)(b * 512 + o)) * 64 + hh) * 64 + w4) = v;
      }
    }
}

extern "C" void kernel_launch(void* const* d_in, const int* in_sizes, int n_in,
                              void* d_out, int out_size, void* d_ws, size_t ws_size,
                              hipStream_t stream) {
  const float* x    = (const float*)d_in[0];
  const float* wsp  = (const float*)d_in[1];
  const float* wpw  = (const float*)d_in[2];
  const float* bias = (const float*)d_in[3];
  const float* cw   = (const float*)d_in[4];
  const float* cb   = (const float*)d_in[5];
  float* out = (float*)d_out;

  char* ws = (char*)d_ws;
  float* mean = (float*)ws;                              // 4096 f32
  float* rstd = (float*)(ws + 16384);                    // 4096 f32
  unsigned short* wT2 = (unsigned short*)(ws + 32768);   // 4.5 MB
  unsigned short* mid = (unsigned short*)(ws + 32768 + 9 * 512 * 512 * 2); // 32 MB

  k_stats<<<4096, 256, 0, stream>>>(x, mean, rstd);
  k_wprep<<<9216, 256, 0, stream>>>(cw, wT2);
  k_mid<<<512, 256, 0, stream>>>(x, wsp, wpw, bias, mean, rstd, mid);
  k_conv<<<256, 512, 0, stream>>>(wT2, mid, cb, out);
}